// Round 1
// baseline (221.755 us; speedup 1.0000x reference)
//
#include <hip/hip_runtime.h>

// Reference: out = x @ eye(4096) == x. Pure float32 copy, memory-bound.
// 8192*4096 floats = 33,554,432 elements = 8,388,608 float4s.
// float4 copy measured at 6.29 TB/s on MI355X (learn_hip m13).

__global__ __launch_bounds__(256) void copy_f4(const float4* __restrict__ in,
                                               float4* __restrict__ out,
                                               int n4) {
    int i = blockIdx.x * blockDim.x + threadIdx.x;
    if (i < n4) {
        out[i] = in[i];
    }
}

extern "C" void kernel_launch(void* const* d_in, const int* in_sizes, int n_in,
                              void* d_out, int out_size, void* d_ws, size_t ws_size,
                              hipStream_t stream) {
    const float4* x = (const float4*)d_in[0];
    float4* out = (float4*)d_out;
    int n4 = out_size / 4;  // 33,554,432 / 4 = 8,388,608
    int block = 256;
    int grid = (n4 + block - 1) / block;  // 32768 blocks
    copy_f4<<<grid, block, 0, stream>>>(x, out, n4);
}